// Round 2
// baseline (707.262 us; speedup 1.0000x reference)
//
#include <hip/hip_runtime.h>
#include <math.h>

// Problem constants (fixed by setup_inputs)
constexpr int Mr = 16384;   // B*T
constexpr int Nn = 4096;    // G*V
constexpr int Kk = 1024;    // Din
constexpr int Gg = 4;
constexpr int Vv = 1024;
constexpr int Dd = 128;

typedef __attribute__((ext_vector_type(8))) short bf16x8;
typedef __attribute__((ext_vector_type(8))) unsigned short ushort8x;
typedef __attribute__((ext_vector_type(4))) float f32x4;

__device__ inline ushort f32_to_bf16(float x) {
    unsigned u = __float_as_uint(x);
    u += 0x7FFFu + ((u >> 16) & 1u);
    return (ushort)(u >> 16);
}

__device__ inline void gload16(const void* g, void* lds) {
    // async global->LDS, 16B per lane; LDS dest = wave-uniform base + lane*16
    __builtin_amdgcn_global_load_lds(
        (const __attribute__((address_space(1))) unsigned int*)g,
        (__attribute__((address_space(3))) unsigned int*)lds, 16, 0, 0);
}

// ---------------------------------------------------------------------------
// Kernel 0a: A fp32 -> bf16 (RNE).  96 MB traffic.
// ---------------------------------------------------------------------------
__global__ __launch_bounds__(256) void convert_a(
    const float* __restrict__ A, ushort* __restrict__ Abf)
{
    const size_t i = ((size_t)blockIdx.x * 256 + threadIdx.x) * 8;
    const float4 v0 = *(const float4*)(A + i);
    const float4 v1 = *(const float4*)(A + i + 4);
    ushort8x h;
    h[0] = f32_to_bf16(v0.x); h[1] = f32_to_bf16(v0.y);
    h[2] = f32_to_bf16(v0.z); h[3] = f32_to_bf16(v0.w);
    h[4] = f32_to_bf16(v1.x); h[5] = f32_to_bf16(v1.y);
    h[6] = f32_to_bf16(v1.z); h[7] = f32_to_bf16(v1.w);
    *(ushort8x*)(Abf + i) = h;
}

// ---------------------------------------------------------------------------
// Kernel 0b: W [K][N] fp32 -> Wt [N][K] bf16 (LDS tile transpose). 24 MB.
// ---------------------------------------------------------------------------
__global__ __launch_bounds__(256) void convert_wt(
    const float* __restrict__ W, ushort* __restrict__ Wt)
{
    __shared__ ushort t[64][80];            // 80: keeps 16B-aligned rows
    const int n0 = blockIdx.x * 64;
    const int k0 = blockIdx.y * 64;
    const int tid = threadIdx.x;

    const int kl = tid >> 2;                // 0..63
    const int nl = (tid & 3) * 16;          // 0,16,32,48
    const float* src = W + (size_t)(k0 + kl) * Nn + n0 + nl;
#pragma unroll
    for (int j = 0; j < 16; j += 4) {
        const float4 v = *(const float4*)(src + j);
        t[nl + j + 0][kl] = f32_to_bf16(v.x);
        t[nl + j + 1][kl] = f32_to_bf16(v.y);
        t[nl + j + 2][kl] = f32_to_bf16(v.z);
        t[nl + j + 3][kl] = f32_to_bf16(v.w);
    }
    __syncthreads();
    const int nr = tid >> 2;                // 0..63
    const int kc = (tid & 3) * 16;          // 0,16,32,48
    ushort* dst = Wt + (size_t)(n0 + nr) * Kk + k0 + kc;
    *(ushort8x*)(dst)     = *(const ushort8x*)&t[nr][kc];
    *(ushort8x*)(dst + 8) = *(const ushort8x*)&t[nr][kc + 8];
}

// ---------------------------------------------------------------------------
// Kernel 1: C = Abf @ Wt^T + b.  256x256 tile, BK=32, 8 waves (2M x 4N),
// triple-buffered LDS (3 x 32 KB), counted-vmcnt phase schedule:
//   per tile t (2 phases):
//     pA: stage A-halves of t+2 -> buf[(t+2)%3]; vmcnt(6); s_barrier;
//         ds_read B(4)+A0(4); lgkmcnt(0); setprio(1); 16 MFMA; setprio(0)
//     pB: stage B-halves of t+2; ds_read A1(4); lgkmcnt(0);
//         setprio(1); 16 MFMA; setprio(0); s_barrier
// Ledger: loads issued after tile t's last stage = 6 -> vmcnt(6) proves
// tile t landed; 3 half-tiles always in flight (never drains to 0).
// End-of-tile barrier orders reads of buf[t%3] before t+3's stages (issued
// at t+1.pA) can land there.  Tail tiles: vmcnt(4) then vmcnt(0).
// LDS swizzle (both-sides, rule #21): chunk ^= (row>>1)&3 on global source
// and on ds_read addr; gload dest stays linear.  2-way bank access = free.
// Accumulation order over k identical to previous kernel -> bit-identical C.
// ---------------------------------------------------------------------------
constexpr int NT = Kk / 32;   // 32 K-tiles

__global__ __launch_bounds__(512, 2) void gemm_bf16_256(
    const ushort* __restrict__ Abf,  // [Mr][Kk] bf16
    const ushort* __restrict__ Bt,   // [Nn][Kk] bf16 (W transposed)
    const float* __restrict__ bvec,  // [Nn]
    float* __restrict__ C)           // [Mr][Nn]
{
    __shared__ ushort lds[3 * 16384];  // 96 KB: slot s = A@s*16384, B@+8192

    const int tid  = threadIdx.x;
    const int lane = tid & 63;
    const int w    = tid >> 6;        // wave 0..7
    const int wm   = w >> 2;          // 0..1  (M half)
    const int wn   = w & 3;           // 0..3  (N quarter)
    const int quad = lane >> 4;
    const int l16  = lane & 15;

    // XCD-aware bijective swizzle (1024 blocks % 8 == 0): each XCD owns 2
    // n-tiles (1 MB of Wt resident in its L2), streams A m-tiles through.
    const int bid = blockIdx.x;
    const int xcd = bid & 7;
    const int idx = bid >> 3;         // 0..127
    const int n_t = xcd * 2 + (idx >> 6);   // 0..15
    const int m_t = idx & 63;               // 0..63
    const int m0  = m_t << 8;
    const int n0  = n_t << 8;

    // staging: thread -> row tid>>2 (0..127 within half), 16B chunk tid&3,
    // source column pre-swizzled (dest linear)
    const int srow = tid >> 2;
    const int sch  = (tid & 3) ^ ((srow >> 1) & 3);
    const ushort* pa = Abf + (size_t)(m0 + srow) * Kk + sch * 8;
    const ushort* pb = Bt  + (size_t)(n0 + srow) * Kk + sch * 8;
    const int dst_w = w << 9;         // wave-uniform dest base (ushorts)

    // precomputed swizzled frag offsets (ushorts within A/B region)
    int offB[4], offA0[4], offA1[4];
#pragma unroll
    for (int ni = 0; ni < 4; ++ni) {
        const int r = wn * 64 + ni * 16 + l16;
        offB[ni] = r * 32 + ((quad ^ ((r >> 1) & 3)) << 3);
    }
#pragma unroll
    for (int mi = 0; mi < 4; ++mi) {
        const int r0 = wm * 128 + mi * 16 + l16;
        offA0[mi] = r0 * 32 + ((quad ^ ((r0 >> 1) & 3)) << 3);
        const int r1 = r0 + 64;
        offA1[mi] = r1 * 32 + ((quad ^ ((r1 >> 1) & 3)) << 3);
    }

    f32x4 acc[8][4];
#pragma unroll
    for (int i = 0; i < 8; i++)
#pragma unroll
        for (int j = 0; j < 4; j++) acc[i][j] = (f32x4)(0.0f);

    // prologue: stage tiles 0 and 1 (order defines the vmcnt ledger)
#pragma unroll
    for (int tt = 0; tt < 2; ++tt) {
        gload16(pa + (size_t)(0) * Kk + tt * 32,   &lds[tt * 16384 + 0    + dst_w]);
        gload16(pa + (size_t)(128) * Kk + tt * 32, &lds[tt * 16384 + 4096 + dst_w]);
        gload16(pb + (size_t)(0) * Kk + tt * 32,   &lds[tt * 16384 + 8192 + dst_w]);
        gload16(pb + (size_t)(128) * Kk + tt * 32, &lds[tt * 16384 + 12288 + dst_w]);
    }

    int slot = 0;
#pragma unroll 1
    for (int t = 0; t < NT; ++t) {
        const int snext = (slot + 2 >= 3) ? slot - 1 : slot + 2;  // (t+2)%3
        const ushort* As = &lds[slot * 16384];
        const ushort* Bs = &lds[slot * 16384 + 8192];

        // ---- phase A: stage A-halves of t+2, prove tile t landed ----
        if (t + 2 < NT) {
            gload16(pa + (size_t)(0) * Kk + (t + 2) * 32,
                    &lds[snext * 16384 + 0 + dst_w]);
            gload16(pa + (size_t)(128) * Kk + (t + 2) * 32,
                    &lds[snext * 16384 + 4096 + dst_w]);
            asm volatile("s_waitcnt vmcnt(6)" ::: "memory");
        } else if (t + 1 < NT) {
            asm volatile("s_waitcnt vmcnt(4)" ::: "memory");
        } else {
            asm volatile("s_waitcnt vmcnt(0)" ::: "memory");
        }
        __builtin_amdgcn_sched_barrier(0);
        __builtin_amdgcn_s_barrier();
        __builtin_amdgcn_sched_barrier(0);

        bf16x8 bfr[4], afr[4];
#pragma unroll
        for (int ni = 0; ni < 4; ++ni) bfr[ni] = *(const bf16x8*)&Bs[offB[ni]];
#pragma unroll
        for (int mi = 0; mi < 4; ++mi) afr[mi] = *(const bf16x8*)&As[offA0[mi]];
        asm volatile("s_waitcnt lgkmcnt(0)" ::: "memory");
        __builtin_amdgcn_sched_barrier(0);
        __builtin_amdgcn_s_setprio(1);
#pragma unroll
        for (int mi = 0; mi < 4; ++mi)
#pragma unroll
            for (int ni = 0; ni < 4; ++ni)
                acc[mi][ni] = __builtin_amdgcn_mfma_f32_16x16x32_bf16(
                    afr[mi], bfr[ni], acc[mi][ni], 0, 0, 0);
        __builtin_amdgcn_s_setprio(0);

        // ---- phase B: stage B-halves of t+2, compute lower M half ----
        if (t + 2 < NT) {
            gload16(pb + (size_t)(0) * Kk + (t + 2) * 32,
                    &lds[snext * 16384 + 8192 + dst_w]);
            gload16(pb + (size_t)(128) * Kk + (t + 2) * 32,
                    &lds[snext * 16384 + 12288 + dst_w]);
        }
        bf16x8 afr2[4];
#pragma unroll
        for (int mi = 0; mi < 4; ++mi) afr2[mi] = *(const bf16x8*)&As[offA1[mi]];
        asm volatile("s_waitcnt lgkmcnt(0)" ::: "memory");
        __builtin_amdgcn_sched_barrier(0);
        __builtin_amdgcn_s_setprio(1);
#pragma unroll
        for (int mi = 0; mi < 4; ++mi)
#pragma unroll
            for (int ni = 0; ni < 4; ++ni)
                acc[mi + 4][ni] = __builtin_amdgcn_mfma_f32_16x16x32_bf16(
                    afr2[mi], bfr[ni], acc[mi + 4][ni], 0, 0, 0);
        __builtin_amdgcn_s_setprio(0);
        __builtin_amdgcn_s_barrier();   // reads of buf[slot] done before t+3 stages
        __builtin_amdgcn_sched_barrier(0);

        slot = (slot + 1 >= 3) ? 0 : slot + 1;
    }

    // epilogue: bias + store (D layout: row = quad*4 + r, col = l16)
    float bb[4];
#pragma unroll
    for (int ni = 0; ni < 4; ni++)
        bb[ni] = bvec[n0 + wn * 64 + ni * 16 + l16];
#pragma unroll
    for (int mi = 0; mi < 8; mi++) {
        const int mbase = m0 + wm * 128 + mi * 16 + quad * 4;
#pragma unroll
        for (int ni = 0; ni < 4; ni++) {
            const int n = n0 + wn * 64 + ni * 16 + l16;
            float* cp = C + (size_t)mbase * Nn + n;
#pragma unroll
            for (int r = 0; r < 4; r++)
                cp[(size_t)r * Nn] = acc[mi][ni][r] + bb[ni];
        }
    }
}

// ---------------------------------------------------------------------------
// Kernel 2: per (b,t,g) row of V=1024:
//   l = (logit+gumbel)/TAU; argmax (first-index ties, fp64 recompute of
//   near-ties, block-parallel); softmax in-place; ids; quantized.
// ---------------------------------------------------------------------------
__global__ __launch_bounds__(256) void vq_epilogue(
    float* __restrict__ logits,        // [Mr*Gg][Vv] -> probs in-place
    const float* __restrict__ gumbel,  // [Mr*Gg][Vv]
    const int* __restrict__ paddings,  // [Mr]
    const float* __restrict__ A,       // inputs [Mr][Kk] fp32
    const float* __restrict__ Wm,      // [Kk][Nn] fp32
    const float* __restrict__ bvec,    // [Nn]
    const float* __restrict__ codebook,// [Gg][Vv][Dd]
    float* __restrict__ ids_out,       // [Mr*Gg] as float
    float* __restrict__ quant_out)     // [Mr*Gg][Dd]
{
    const int idx = blockIdx.x;       // m*G + g
    const int m   = idx >> 2;
    const int g   = idx & 3;
    const int tid = threadIdx.x;
    const int w    = tid >> 6;
    const int lane = tid & 63;
    float* row = logits + (size_t)idx * Vv;

    if (paddings[m] != 0) {
        *(float4*)(row + tid * 4) = float4{0.f, 0.f, 0.f, 0.f};
        if (tid == 0) ids_out[idx] = -1.0f;
        if (tid < 32) *(float4*)(quant_out + (size_t)idx * Dd + tid * 4) = float4{0.f, 0.f, 0.f, 0.f};
        return;
    }

    const float* grow = gumbel + (size_t)idx * Vv;
    const float4 lr = *(const float4*)(row + tid * 4);
    const float4 gr = *(const float4*)(grow + tid * 4);
    float lv[4] = {(lr.x + gr.x) * 0.5f, (lr.y + gr.y) * 0.5f,
                   (lr.z + gr.z) * 0.5f, (lr.w + gr.w) * 0.5f};

    float bv1 = -1e30f, bv2 = -1e30f;
    int   bi1 = 0;
#pragma unroll
    for (int jj = 0; jj < 4; jj++) {
        const int v = tid * 4 + jj;
        if (lv[jj] > bv1) { bv2 = bv1; bv1 = lv[jj]; bi1 = v; }
        else if (lv[jj] > bv2) bv2 = lv[jj];
    }

#pragma unroll
    for (int off = 1; off < 64; off <<= 1) {
        const float ov1 = __shfl_xor(bv1, off);
        const float ov2 = __shfl_xor(bv2, off);
        const int   oi1 = __shfl_xor(bi1, off);
        if (ov1 > bv1 || (ov1 == bv1 && oi1 < bi1)) {
            bv2 = fmaxf(bv1, ov2); bv1 = ov1; bi1 = oi1;
        } else {
            bv2 = fmaxf(bv2, ov1);
        }
    }

    __shared__ float  sv1[4], sv2[4], ssum[4];
    __shared__ int    si1[4];
    __shared__ int    s_cnt;
    __shared__ int    s_cand[32];
    __shared__ double sdv[4];

    if (lane == 0) { sv1[w] = bv1; sv2[w] = bv2; si1[w] = bi1; }
    __syncthreads();

    float gv1 = sv1[0], gv2 = sv2[0];
    int   gi1 = si1[0];
#pragma unroll
    for (int ww = 1; ww < 4; ww++) {
        const float ov1 = sv1[ww], ov2 = sv2[ww];
        const int   oi  = si1[ww];
        if (ov1 > gv1 || (ov1 == gv1 && oi < gi1)) {
            gv2 = fmaxf(gv1, ov2); gv1 = ov1; gi1 = oi;
        } else {
            gv2 = fmaxf(gv2, ov1);
        }
    }
    const float gmax = gv1;
    const float gap  = gv1 - gv2;
    int id = gi1;

    const float MARGIN = 0.02f;   // >= 2x worst bf16-GEMM logit error
    if (gap < MARGIN) {           // block-uniform branch
        if (tid == 0) s_cnt = 0;
        __syncthreads();
#pragma unroll
        for (int jj = 0; jj < 4; jj++) {
            if (lv[jj] >= gmax - MARGIN) {
                const int p = atomicAdd(&s_cnt, 1);
                if (p < 32) s_cand[p] = tid * 4 + jj;
            }
        }
        __syncthreads();
        const int ncand = min(s_cnt, 32);
        double bdv = -1e300;
        int    bdi = 1 << 30;
        const float* arow = A + (size_t)m * Kk;
        const float4 av = *(const float4*)(arow + tid * 4);
        for (int c = 0; c < ncand; ++c) {
            const int v = s_cand[c];
            const float* wcol = Wm + (g << 10) + v;
            const size_t kb = (size_t)tid * 4;
            double part = (double)av.x * (double)wcol[(kb + 0) * Nn]
                        + (double)av.y * (double)wcol[(kb + 1) * Nn]
                        + (double)av.z * (double)wcol[(kb + 2) * Nn]
                        + (double)av.w * (double)wcol[(kb + 3) * Nn];
#pragma unroll
            for (int off = 1; off < 64; off <<= 1)
                part += __shfl_xor(part, off);
            if (lane == 0) sdv[w] = part;
            __syncthreads();
            const double dot = sdv[0] + sdv[1] + sdv[2] + sdv[3]
                             + (double)bvec[(g << 10) + v];
            const double val = (dot + (double)grow[v]) * 0.5;
            if (val > bdv || (val == bdv && v < bdi)) { bdv = val; bdi = v; }
            __syncthreads();
        }
        id = bdi;
    }

    float ev[4];
    float se = 0.f;
#pragma unroll
    for (int jj = 0; jj < 4; jj++) { ev[jj] = __expf(lv[jj] - gmax); se += ev[jj]; }
#pragma unroll
    for (int off = 1; off < 64; off <<= 1)
        se += __shfl_xor(se, off);
    if (lane == 0) ssum[w] = se;
    __syncthreads();
    const float inv = 1.0f / (ssum[0] + ssum[1] + ssum[2] + ssum[3]);
    *(float4*)(row + tid * 4) = float4{ev[0] * inv, ev[1] * inv, ev[2] * inv, ev[3] * inv};

    if (tid == 0) ids_out[idx] = (float)id;
    if (tid < 32)
        *(float4*)(quant_out + (size_t)idx * Dd + tid * 4) =
            *(const float4*)(codebook + (size_t)(((g << 10) + id) << 7) + tid * 4);
}

// ---------------------------------------------------------------------------
extern "C" void kernel_launch(void* const* d_in, const int* in_sizes, int n_in,
                              void* d_out, int out_size, void* d_ws, size_t ws_size,
                              hipStream_t stream) {
    const float* inputs   = (const float*)d_in[0];
    const int*   paddings = (const int*)d_in[1];
    const float* gumbel   = (const float*)d_in[2];
    const float* W        = (const float*)d_in[3];
    const float* bvec     = (const float*)d_in[4];
    const float* codebook = (const float*)d_in[5];

    float* out       = (float*)d_out;
    float* ids_out   = out;                                           // 65536
    float* quant_out = out + (size_t)Mr * Gg;                         // 8388608
    float* probs_out = out + (size_t)Mr * Gg + (size_t)Mr * Gg * Dd;  // 67108864

    // bf16 A: 32 MB scratch in the quant region (rewritten by the epilogue
    // after the GEMM has consumed it).  bf16 W^T: 8 MB of d_ws.
    ushort* Abf = (ushort*)quant_out;
    ushort* Wt  = (ushort*)d_ws;

    convert_a<<<(Mr * Kk) / (256 * 8), 256, 0, stream>>>(inputs, Abf);
    convert_wt<<<dim3(Nn / 64, Kk / 64), 256, 0, stream>>>(W, Wt);

    gemm_bf16_256<<<(Mr / 256) * (Nn / 256), 512, 0, stream>>>(Abf, Wt, bvec, probs_out);

    vq_epilogue<<<Mr * Gg, 256, 0, stream>>>(probs_out, gumbel, paddings,
                                             inputs, W, bvec, codebook,
                                             ids_out, quant_out);
}

// Round 3
// 624.968 us; speedup vs baseline: 1.1317x; 1.1317x over previous
//
#include <hip/hip_runtime.h>
#include <math.h>

// Problem constants (fixed by setup_inputs)
constexpr int Mr = 16384;   // B*T
constexpr int Nn = 4096;    // G*V
constexpr int Kk = 1024;    // Din
constexpr int Gg = 4;
constexpr int Vv = 1024;
constexpr int Dd = 128;

typedef __attribute__((ext_vector_type(8))) short bf16x8;
typedef __attribute__((ext_vector_type(8))) unsigned short ushort8x;
typedef __attribute__((ext_vector_type(4))) float f32x4;

__device__ inline ushort f32_to_bf16(float x) {
    unsigned u = __float_as_uint(x);
    u += 0x7FFFu + ((u >> 16) & 1u);
    return (ushort)(u >> 16);
}

__device__ inline void gload16(const void* g, void* lds) {
    // async global->LDS, 16B per lane; LDS dest = wave-uniform base + lane*16
    __builtin_amdgcn_global_load_lds(
        (const __attribute__((address_space(1))) unsigned int*)g,
        (__attribute__((address_space(3))) unsigned int*)lds, 16, 0, 0);
}

// ---------------------------------------------------------------------------
// Kernel P: deterministic compaction of non-padded rows.
// cmap[j] = m of j-th non-padded row (thread-interleaved partition: thread t
// owns rows {t, 256+t, ...} -> order is fixed, no atomics, bit-reproducible).
// mp[0] = count of non-padded rows.
// ---------------------------------------------------------------------------
__global__ __launch_bounds__(256) void compact_rows(
    const int* __restrict__ paddings, int* __restrict__ cmap,
    int* __restrict__ mp)
{
    const int t = threadIdx.x;
    __shared__ int s[256];
    int c = 0;
#pragma unroll 4
    for (int k = 0; k < 64; ++k) c += (paddings[k * 256 + t] == 0);
    s[t] = c;
    __syncthreads();
    // Hillis-Steele inclusive scan over 256 thread counts
    for (int d = 1; d < 256; d <<= 1) {
        const int v = (t >= d) ? s[t - d] : 0;
        __syncthreads();
        s[t] += v;
        __syncthreads();
    }
    int pos = s[t] - c;   // exclusive prefix
    for (int k = 0; k < 64; ++k) {
        const int m = k * 256 + t;
        if (paddings[m] == 0) cmap[pos++] = m;
    }
    if (t == 255) mp[0] = s[255];
}

// ---------------------------------------------------------------------------
// Kernel 0a: compacted A rows fp32 -> bf16 (RNE).  ~48 MB traffic.
// Row j of Abf = bf16(A[cmap[j]]); rows [Mp, ceil128(Mp)) zero-filled so the
// GEMM's last tile reads defined data (its stores are guarded anyway).
// ---------------------------------------------------------------------------
__global__ __launch_bounds__(256) void convert_a_compact(
    const float* __restrict__ A, const int* __restrict__ cmap,
    const int* __restrict__ mp, ushort* __restrict__ Abf)
{
    const int Mp  = mp[0];
    const int Mpr = (Mp + 127) & ~127;
    const int j   = blockIdx.x * 2 + (threadIdx.x >> 7);
    if (j >= Mpr) return;
    const int col = (threadIdx.x & 127) * 8;
    ushort8x h = (ushort8x)0;
    if (j < Mp) {
        const float* src = A + (size_t)cmap[j] * Kk + col;
        const float4 v0 = *(const float4*)(src);
        const float4 v1 = *(const float4*)(src + 4);
        h[0] = f32_to_bf16(v0.x); h[1] = f32_to_bf16(v0.y);
        h[2] = f32_to_bf16(v0.z); h[3] = f32_to_bf16(v0.w);
        h[4] = f32_to_bf16(v1.x); h[5] = f32_to_bf16(v1.y);
        h[6] = f32_to_bf16(v1.z); h[7] = f32_to_bf16(v1.w);
    }
    *(ushort8x*)(Abf + (size_t)j * Kk + col) = h;
}

// ---------------------------------------------------------------------------
// Kernel 0b: W [K][N] fp32 -> Wt [N][K] bf16 (LDS tile transpose). 24 MB.
// ---------------------------------------------------------------------------
__global__ __launch_bounds__(256) void convert_wt(
    const float* __restrict__ W, ushort* __restrict__ Wt)
{
    __shared__ ushort t[64][80];            // 80: keeps 16B-aligned rows
    const int n0 = blockIdx.x * 64;
    const int k0 = blockIdx.y * 64;
    const int tid = threadIdx.x;

    const int kl = tid >> 2;                // 0..63
    const int nl = (tid & 3) * 16;          // 0,16,32,48
    const float* src = W + (size_t)(k0 + kl) * Nn + n0 + nl;
#pragma unroll
    for (int j = 0; j < 16; j += 4) {
        const float4 v = *(const float4*)(src + j);
        t[nl + j + 0][kl] = f32_to_bf16(v.x);
        t[nl + j + 1][kl] = f32_to_bf16(v.y);
        t[nl + j + 2][kl] = f32_to_bf16(v.z);
        t[nl + j + 3][kl] = f32_to_bf16(v.w);
    }
    __syncthreads();
    const int nr = tid >> 2;                // 0..63
    const int kc = (tid & 3) * 16;          // 0,16,32,48
    ushort* dst = Wt + (size_t)(n0 + nr) * Kk + k0 + kc;
    *(ushort8x*)(dst)     = *(const ushort8x*)&t[nr][kc];
    *(ushort8x*)(dst + 8) = *(const ushort8x*)&t[nr][kc + 8];
}

// ---------------------------------------------------------------------------
// Kernel 1: C[cmap[j]] = Abf[j] @ Wt^T + b over compacted rows only.
// Proven round-1 structure: 128x128 tile, BK=64, 4 waves 2x2,
// global_load_lds w=16 with both-sides XOR swizzle (rule #21); grid is the
// fixed worst case, blocks beyond ceil128(Mp) exit immediately; C-store is
// scattered through cmap with a per-row guard.  Per-row accumulation order
// identical to previous rounds -> bit-identical logits.
// ---------------------------------------------------------------------------
__global__ __launch_bounds__(256, 2) void gemm_bf16(
    const ushort* __restrict__ Abf,  // [<=Mr][Kk] bf16, compacted
    const ushort* __restrict__ Bt,   // [Nn][Kk] bf16 (W transposed)
    const float* __restrict__ bvec,  // [Nn]
    const int* __restrict__ cmap,    // compact -> original row
    const int* __restrict__ mp,      // [0] = Mp
    float* __restrict__ C)           // [Mr][Nn]
{
    __shared__ ushort Ah[128 * 64];  // 16 KB, linear (global_load_lds dest)
    __shared__ ushort Bh[128 * 64];  // 16 KB

    const int tid  = threadIdx.x;
    const int lane = tid & 63;
    const int w    = tid >> 6;
    const int wm   = w >> 1;
    const int wn   = w & 1;
    const int quad = lane >> 4;
    const int l16  = lane & 15;

    // XCD-aware swizzle: each XCD owns a 4-wide n-panel (1 MB of Wt in L2),
    // streams A through it. bid -> (m_t 0..127, n_t 0..31), bijective.
    const int bid = blockIdx.x;
    const int j   = bid >> 3;
    const int n_t = ((bid & 7) << 2) + (j & 3);
    const int m_t = j >> 2;
    const int m0  = m_t << 7;
    const int n0  = n_t << 7;

    const int Mp = mp[0];
    if (m0 >= ((Mp + 127) & ~127)) return;   // block fully past compacted rows

    // staging: thread covers rows srow + it*32, 16B chunk (tid&7), swizzled src
    const int srow = tid >> 3;                              // 0..31
    const int scol = ((tid & 7) ^ (srow & 7)) << 3;         // swizzled k-offset
    const ushort* pa = Abf + (size_t)(m0 + srow) * Kk + scol;
    const ushort* pb = Bt  + (size_t)(n0 + srow) * Kk + scol;

    const int xr = (l16 & 7) << 3;                          // read-side swizzle

    f32x4 acc[4][4];
#pragma unroll
    for (int i = 0; i < 4; i++)
#pragma unroll
        for (int jj = 0; jj < 4; jj++) acc[i][jj] = (f32x4)(0.0f);

    for (int k0 = 0; k0 < Kk; k0 += 64) {
#pragma unroll
        for (int it = 0; it < 4; ++it)
            gload16(pa + (size_t)it * 32 * Kk + k0, &Ah[it * 2048 + w * 512]);
#pragma unroll
        for (int it = 0; it < 4; ++it)
            gload16(pb + (size_t)it * 32 * Kk + k0, &Bh[it * 2048 + w * 512]);
        __syncthreads();   // compiler drains vmcnt(0) here -> tile ready

#pragma unroll
        for (int kh = 0; kh < 2; ++kh) {
            bf16x8 af[4], bfr[4];
#pragma unroll
            for (int mi = 0; mi < 4; ++mi) {
                const int r = wm * 64 + mi * 16 + l16;
                af[mi] = *(const bf16x8*)&Ah[r * 64 + ((kh * 32 + quad * 8) ^ xr)];
            }
#pragma unroll
            for (int ni = 0; ni < 4; ++ni) {
                const int r = wn * 64 + ni * 16 + l16;
                bfr[ni] = *(const bf16x8*)&Bh[r * 64 + ((kh * 32 + quad * 8) ^ xr)];
            }
#pragma unroll
            for (int mi = 0; mi < 4; ++mi)
#pragma unroll
                for (int ni = 0; ni < 4; ++ni)
                    acc[mi][ni] = __builtin_amdgcn_mfma_f32_16x16x32_bf16(
                        af[mi], bfr[ni], acc[mi][ni], 0, 0, 0);
        }
        __syncthreads();   // all reads done before next stage overwrites
    }

    // epilogue: bias + scattered store via cmap (D: row = quad*4 + r, col = l16)
    float bb[4];
#pragma unroll
    for (int ni = 0; ni < 4; ni++)
        bb[ni] = bvec[n0 + wn * 64 + ni * 16 + l16];
#pragma unroll
    for (int mi = 0; mi < 4; mi++) {
        const int j0 = m0 + wm * 64 + mi * 16 + quad * 4;   // compact row base
        if (j0 >= Mp) continue;
        const int4 cm = *(const int4*)&cmap[j0];            // j0 is 4-aligned
        const int cr[4] = {cm.x, cm.y, cm.z, cm.w};
#pragma unroll
        for (int ni = 0; ni < 4; ni++) {
            const int n = n0 + wn * 64 + ni * 16 + l16;
#pragma unroll
            for (int r = 0; r < 4; r++)
                if (j0 + r < Mp)
                    C[(size_t)cr[r] * Nn + n] = acc[mi][ni][r] + bb[ni];
        }
    }
}

// ---------------------------------------------------------------------------
// Kernel 2: per (b,t,g) row of V=1024:
//   l = (logit+gumbel)/TAU; argmax (first-index ties, fp64 recompute of
//   near-ties, block-parallel); softmax in-place; ids; quantized.
// Padded rows never read logits (which are now uncomputed for them).
// ---------------------------------------------------------------------------
__global__ __launch_bounds__(256) void vq_epilogue(
    float* __restrict__ logits,        // [Mr*Gg][Vv] -> probs in-place
    const float* __restrict__ gumbel,  // [Mr*Gg][Vv]
    const int* __restrict__ paddings,  // [Mr]
    const float* __restrict__ A,       // inputs [Mr][Kk] fp32
    const float* __restrict__ Wm,      // [Kk][Nn] fp32
    const float* __restrict__ bvec,    // [Nn]
    const float* __restrict__ codebook,// [Gg][Vv][Dd]
    float* __restrict__ ids_out,       // [Mr*Gg] as float
    float* __restrict__ quant_out)     // [Mr*Gg][Dd]
{
    const int idx = blockIdx.x;       // m*G + g
    const int m   = idx >> 2;
    const int g   = idx & 3;
    const int tid = threadIdx.x;
    const int w    = tid >> 6;
    const int lane = tid & 63;
    float* row = logits + (size_t)idx * Vv;

    if (paddings[m] != 0) {
        *(float4*)(row + tid * 4) = float4{0.f, 0.f, 0.f, 0.f};
        if (tid == 0) ids_out[idx] = -1.0f;
        if (tid < 32) *(float4*)(quant_out + (size_t)idx * Dd + tid * 4) = float4{0.f, 0.f, 0.f, 0.f};
        return;
    }

    const float* grow = gumbel + (size_t)idx * Vv;
    const float4 lr = *(const float4*)(row + tid * 4);
    const float4 gr = *(const float4*)(grow + tid * 4);
    float lv[4] = {(lr.x + gr.x) * 0.5f, (lr.y + gr.y) * 0.5f,
                   (lr.z + gr.z) * 0.5f, (lr.w + gr.w) * 0.5f};

    float bv1 = -1e30f, bv2 = -1e30f;
    int   bi1 = 0;
#pragma unroll
    for (int jj = 0; jj < 4; jj++) {
        const int v = tid * 4 + jj;
        if (lv[jj] > bv1) { bv2 = bv1; bv1 = lv[jj]; bi1 = v; }
        else if (lv[jj] > bv2) bv2 = lv[jj];
    }

#pragma unroll
    for (int off = 1; off < 64; off <<= 1) {
        const float ov1 = __shfl_xor(bv1, off);
        const float ov2 = __shfl_xor(bv2, off);
        const int   oi1 = __shfl_xor(bi1, off);
        if (ov1 > bv1 || (ov1 == bv1 && oi1 < bi1)) {
            bv2 = fmaxf(bv1, ov2); bv1 = ov1; bi1 = oi1;
        } else {
            bv2 = fmaxf(bv2, ov1);
        }
    }

    __shared__ float  sv1[4], sv2[4], ssum[4];
    __shared__ int    si1[4];
    __shared__ int    s_cnt;
    __shared__ int    s_cand[32];
    __shared__ double sdv[4];

    if (lane == 0) { sv1[w] = bv1; sv2[w] = bv2; si1[w] = bi1; }
    __syncthreads();

    float gv1 = sv1[0], gv2 = sv2[0];
    int   gi1 = si1[0];
#pragma unroll
    for (int ww = 1; ww < 4; ww++) {
        const float ov1 = sv1[ww], ov2 = sv2[ww];
        const int   oi  = si1[ww];
        if (ov1 > gv1 || (ov1 == gv1 && oi < gi1)) {
            gv2 = fmaxf(gv1, ov2); gv1 = ov1; gi1 = oi;
        } else {
            gv2 = fmaxf(gv2, ov1);
        }
    }
    const float gmax = gv1;
    const float gap  = gv1 - gv2;
    int id = gi1;

    const float MARGIN = 0.02f;   // >= 2x worst bf16-GEMM logit error
    if (gap < MARGIN) {           // block-uniform branch
        if (tid == 0) s_cnt = 0;
        __syncthreads();
#pragma unroll
        for (int jj = 0; jj < 4; jj++) {
            if (lv[jj] >= gmax - MARGIN) {
                const int p = atomicAdd(&s_cnt, 1);
                if (p < 32) s_cand[p] = tid * 4 + jj;
            }
        }
        __syncthreads();
        const int ncand = min(s_cnt, 32);
        double bdv = -1e300;
        int    bdi = 1 << 30;
        const float* arow = A + (size_t)m * Kk;
        const float4 av = *(const float4*)(arow + tid * 4);
        for (int c = 0; c < ncand; ++c) {
            const int v = s_cand[c];
            const float* wcol = Wm + (g << 10) + v;
            const size_t kb = (size_t)tid * 4;
            double part = (double)av.x * (double)wcol[(kb + 0) * Nn]
                        + (double)av.y * (double)wcol[(kb + 1) * Nn]
                        + (double)av.z * (double)wcol[(kb + 2) * Nn]
                        + (double)av.w * (double)wcol[(kb + 3) * Nn];
#pragma unroll
            for (int off = 1; off < 64; off <<= 1)
                part += __shfl_xor(part, off);
            if (lane == 0) sdv[w] = part;
            __syncthreads();
            const double dot = sdv[0] + sdv[1] + sdv[2] + sdv[3]
                             + (double)bvec[(g << 10) + v];
            const double val = (dot + (double)grow[v]) * 0.5;
            if (val > bdv || (val == bdv && v < bdi)) { bdv = val; bdi = v; }
            __syncthreads();
        }
        id = bdi;
    }

    float ev[4];
    float se = 0.f;
#pragma unroll
    for (int jj = 0; jj < 4; jj++) { ev[jj] = __expf(lv[jj] - gmax); se += ev[jj]; }
#pragma unroll
    for (int off = 1; off < 64; off <<= 1)
        se += __shfl_xor(se, off);
    if (lane == 0) ssum[w] = se;
    __syncthreads();
    const float inv = 1.0f / (ssum[0] + ssum[1] + ssum[2] + ssum[3]);
    *(float4*)(row + tid * 4) = float4{ev[0] * inv, ev[1] * inv, ev[2] * inv, ev[3] * inv};

    if (tid == 0) ids_out[idx] = (float)id;
    if (tid < 32)
        *(float4*)(quant_out + (size_t)idx * Dd + tid * 4) =
            *(const float4*)(codebook + (size_t)(((g << 10) + id) << 7) + tid * 4);
}

// ---------------------------------------------------------------------------
extern "C" void kernel_launch(void* const* d_in, const int* in_sizes, int n_in,
                              void* d_out, int out_size, void* d_ws, size_t ws_size,
                              hipStream_t stream) {
    const float* inputs   = (const float*)d_in[0];
    const int*   paddings = (const int*)d_in[1];
    const float* gumbel   = (const float*)d_in[2];
    const float* W        = (const float*)d_in[3];
    const float* bvec     = (const float*)d_in[4];
    const float* codebook = (const float*)d_in[5];

    float* out       = (float*)d_out;
    float* ids_out   = out;                                           // 65536
    float* quant_out = out + (size_t)Mr * Gg;                         // 8388608
    float* probs_out = out + (size_t)Mr * Gg + (size_t)Mr * Gg * Dd;  // 67108864

    // Scratch placement:
    //   cmap (64 KB) + Mp live at the head of the ids region (256 KB) — both
    //   consumed by convert/gemm, then overwritten by the epilogue's ids.
    //   bf16 compacted A (<=32 MB) in the quant region (rewritten by the
    //   epilogue after the GEMM consumed it).  bf16 W^T: 8 MB of d_ws.
    int*    cmap = (int*)ids_out;
    int*    mp   = cmap + Mr;         // still inside ids region (64 KB + 4 B)
    ushort* Abf  = (ushort*)quant_out;
    ushort* Wt   = (ushort*)d_ws;

    compact_rows<<<1, 256, 0, stream>>>(paddings, cmap, mp);
    convert_a_compact<<<Mr / 2, 256, 0, stream>>>(inputs, cmap, mp, Abf);
    convert_wt<<<dim3(Nn / 64, Kk / 64), 256, 0, stream>>>(W, Wt);

    gemm_bf16<<<(Mr / 128) * (Nn / 128), 256, 0, stream>>>(Abf, Wt, bvec,
                                                           cmap, mp, probs_out);

    vq_epilogue<<<Mr * Gg, 256, 0, stream>>>(probs_out, gumbel, paddings,
                                             inputs, W, bvec, codebook,
                                             ids_out, quant_out);
}